// Round 9
// baseline (68.297 us; speedup 1.0000x reference)
//
#include <hip/hip_runtime.h>
#include <math.h>

namespace {
constexpr int kB = 128;
constexpr int kV = 128256;
constexpr int kSplits = 16;
constexpr int kSplit = kV / kSplits;   // 8016
constexpr int kSplit4 = kSplit / 4;    // 2004 float4
constexpr int kT1 = 256;
constexpr int kE = 8;                  // float4 regs/thread: 8*256=2048 >= 2004
constexpr int kCap = 256;              // candidate cap (== kT1, 1 per thread)
constexpr int kTop = 64;               // max top_k

// monotonic uint key: ascending key <=> ascending float (finite, non-NaN)
__device__ __forceinline__ unsigned fkey(float y) {
  unsigned u = __float_as_uint(y);
  return ((int)u < 0) ? ~u : (u | 0x80000000u);
}
__device__ __forceinline__ float keyinv(unsigned k) {
  unsigned u = (k & 0x80000000u) ? (k & 0x7fffffffu) : ~k;
  return __uint_as_float(u);
}

__global__ __launch_bounds__(kT1) void k_select(
    const float* __restrict__ logits, const float* __restrict__ temps,
    float* __restrict__ wm, float* __restrict__ wS,
    unsigned long long* __restrict__ wpk) {
  const int sp = blockIdx.x, row = blockIdx.y, tid = threadIdx.x;
  const int lane = tid & 63, wid = tid >> 6;
  __shared__ float wred[4];
  __shared__ float ssum[4];
  __shared__ int cnt2[2][4];
  __shared__ unsigned long long cand[kCap];
  __shared__ int scnt;

  if (tid == 0) scnt = 0;
  const float t = temps[row];
  const float invt = 1.0f / t;
  const size_t rowbase = (size_t)row * kV + (size_t)sp * kSplit;
  const float4* in4 = (const float4*)(logits + rowbase);
  const float nI = -INFINITY;

  // READ-ONLY stream: no output stores in this kernel (zero-fill lives in
  // k_sample's streamer blocks). Selection on RAW logits (temperature-
  // invariant order: l -> l/t strictly monotone).
  float4 r[kE];
  float m = nI;
#pragma unroll
  for (int e = 0; e < kE; ++e) {
    int f = tid + e * kT1;
    float4 l;
    if (f < kSplit4) l = in4[f];
    else l = make_float4(nI, nI, nI, nI);
    r[e] = l;
    m = fmaxf(m, fmaxf(fmaxf(l.x, l.y), fmaxf(l.z, l.w)));
  }
  // Wave shfl max (order-exact) + 4-slot combine: 1 barrier.
  for (int o = 32; o; o >>= 1) m = fmaxf(m, __shfl_xor(m, o));
  if (lane == 0) wred[wid] = m;
  __syncthreads();                                   // B1
  const float M = fmaxf(fmaxf(wred[0], wred[1]), fmaxf(wred[2], wred[3]));
  const float My = M / t;     // == max(l/t) bitwise (monotone IEEE div)
  const float negMy = -My;

  // Fast softmax partial sum: exp((l - M)/t) via fma + __expf (v_exp);
  // wave shfl-add butterfly + fixed 4-slot combine (validated absmax 0).
  float s = 0.f;
#pragma unroll
  for (int e = 0; e < kE; ++e) {
    s += __expf(fmaf(r[e].x, invt, negMy));
    s += __expf(fmaf(r[e].y, invt, negMy));
    s += __expf(fmaf(r[e].z, invt, negMy));
    s += __expf(fmaf(r[e].w, invt, negMy));
  }
  for (int o = 32; o; o >>= 1) s += __shfl_xor(s, o);
  if (lane == 0) ssum[wid] = s;
  __syncthreads();                                   // B2
  const float Ssp = ssum[0] + ssum[1] + ssum[2] + ssum[3];

  // Binary-search threshold T (key space), count(l >= T) in [64,256].
  // Ballot+popcount counting; double-buffered slots -> 1 barrier/iter.
  // Warm probes M-3, M-4.5 are bracket hints only; bisection stays exact.
  unsigned lo = 0x00800000u;          // below all finite values
  unsigned hi = fkey(M) + 1;          // count 0
  for (int it = 0; it < 32 && hi - lo > 1; ++it) {
    unsigned mid = lo + ((hi - lo) >> 1);
    if (it == 0) {
      unsigned p0 = fkey(M - 3.0f);
      if (p0 > lo && p0 < hi) mid = p0;
    } else if (it == 1) {
      unsigned p1 = fkey(M - 4.5f);
      if (p1 > lo && p1 < hi) mid = p1;
    }
    const float mf = keyinv(mid);
    int cw = 0;
#pragma unroll
    for (int e = 0; e < kE; ++e) {
      cw += (int)__popcll(__ballot(r[e].x >= mf));
      cw += (int)__popcll(__ballot(r[e].y >= mf));
      cw += (int)__popcll(__ballot(r[e].z >= mf));
      cw += (int)__popcll(__ballot(r[e].w >= mf));
    }
    if (lane == 0) cnt2[it & 1][wid] = cw;
    __syncthreads();                                 // B3..~B5
    const int c = cnt2[it & 1][0] + cnt2[it & 1][1] +
                  cnt2[it & 1][2] + cnt2[it & 1][3];
    if (c >= kTop) { lo = mid; if (c <= kCap) break; }
    else hi = mid;
  }
  const float Tf = keyinv(lo);

  // Collect candidates (raw-float compare; fkey only for survivors).
  // Pack (fkey(l), ~idx): u64 desc == value desc, index asc.
#pragma unroll
  for (int e = 0; e < kE; ++e) {
    int f = tid + e * kT1;
    const float vals[4] = {r[e].x, r[e].y, r[e].z, r[e].w};
#pragma unroll
    for (int j = 0; j < 4; ++j) {
      const float lv = vals[j];
      if (lv >= Tf) {
        int pos = atomicAdd(&scnt, 1);
        if (pos < kCap)
          cand[pos] = ((unsigned long long)fkey(lv) << 32) |
                      (unsigned)~(unsigned)(sp * kSplit + f * 4 + j);
      }
    }
  }
  __syncthreads();                                   // B6
  const int nc = scnt < kCap ? scnt : kCap;
  unsigned long long v = (tid < nc) ? cand[tid] : 0ULL;

  // Bitonic sort 256 desc, one element/thread. Stages with j<64 exchange
  // in-wave via shfl_xor (no barrier); only j in {64,128} use LDS.
  for (int k2 = 2; k2 <= kCap; k2 <<= 1) {
    for (int j = k2 >> 1; j; j >>= 1) {
      unsigned long long o;
      if (j < 64) {
        o = __shfl_xor(v, j);
      } else {
        __syncthreads();         // all prior reads of cand done
        cand[tid] = v;
        __syncthreads();
        o = cand[tid ^ j];
      }
      const bool keep_max = (((tid & k2) == 0) == ((tid & j) == 0));
      v = keep_max ? (o > v ? o : v) : (o < v ? o : v);
    }
  }

  if (tid < kTop)
    wpk[((size_t)row * kSplits + sp) * kTop + tid] = v;
  if (tid == 0) {
    wm[row * kSplits + sp] = My;
    wS[row * kSplits + sp] = Ssp;
  }
}

__global__ __launch_bounds__(kT1) void k_sample(
    const float* __restrict__ temps,
    const int* __restrict__ top_ks, const float* __restrict__ top_ps,
    const float* __restrict__ uin,
    const float* __restrict__ wm, const float* __restrict__ wS,
    const unsigned long long* __restrict__ wpk, float* __restrict__ out) {
  const int sp = blockIdx.x, row = blockIdx.y, tid = threadIdx.x;
  float4* out4 = (float4*)(out + 2 * kB + (size_t)row * kV + (size_t)sp * kSplit);
  const float4 z4 = make_float4(0.f, 0.f, 0.f, 0.f);

  if (sp != 0) {
    // Streamer block: pure zero-fill of this split's output region.
    // Disjoint from the merge block's writes (probs_sort top-64 lives in
    // cols 0..63 = split 0), so no ordering hazard.
#pragma unroll
    for (int e = 0; e < kE; ++e) {
      int f = tid + e * kT1;
      if (f < kSplit4) out4[f] = z4;
    }
    return;
  }

  // Merge block (sp == 0): R8 merge+sample body, then zero-fill the
  // remainder of split 0 (cols 64..8015) at the end so no barrier ever
  // waits on outstanding global stores.
  constexpr int kN = kSplits * kTop;   // 1024
  __shared__ unsigned long long pk[kN];
  __shared__ float mArr[kSplits], sArr[kSplits];
  __shared__ float tv[kTop];
  __shared__ int ti[kTop];
  __shared__ float sv[kTop];
  __shared__ float MS[2];

  if (tid < kSplits) {
    mArr[tid] = wm[row * kSplits + tid];
    sArr[tid] = wS[row * kSplits + tid];
  }
  for (int i = tid; i < kN; i += kT1)
    pk[i] = wpk[(size_t)row * kN + i];
  __syncthreads();
  if (tid == 0) {  // fixed-order merge of split (m, S) partials
    float M = -INFINITY;
    for (int s2 = 0; s2 < kSplits; ++s2) M = fmaxf(M, mArr[s2]);
    float S = 0.f;
    for (int s2 = 0; s2 < kSplits; ++s2) S += expf(mArr[s2] - M) * sArr[s2];
    MS[0] = M; MS[1] = S;
  }

  // Bitonic top-64 merge: 4 rounds of (cross-compare + 6 cleanup stages).
  for (int r = 0; r < 4; ++r) {
    const int pairs = 8 >> r;
    __syncthreads();
    for (int w = tid; w < pairs * 64; w += kT1) {
      int q = w >> 6, i = w & 63;
      int a = q * (128 << r), b = a + (64 << r);
      unsigned long long x = pk[a + i], y = pk[b + 63 - i];
      pk[a + i] = x > y ? x : y;      // top-64 multiset, bitonic order
    }
    for (int j = 32; j; j >>= 1) {    // desc bitonic merge of each kept run
      __syncthreads();
      for (int w = tid; w < pairs * 32; w += kT1) {
        int q = w >> 5, z = w & 31;
        int a = q * (128 << r);
        int i = ((z & ~(j - 1)) << 1) | (z & (j - 1));
        unsigned long long x = pk[a + i], y = pk[a + i + j];
        if (x < y) { pk[a + i] = y; pk[a + i + j] = x; }
      }
    }
  }
  __syncthreads();

  if (tid < kTop) {
    unsigned long long p2 = pk[tid];
    // keys are fkey(raw logit); exact IEEE l/t gives the reference's tv.
    tv[tid] = keyinv((unsigned)(p2 >> 32)) / temps[row];
    ti[tid] = (int)(~(unsigned)(p2 & 0xffffffffu));
  }
  __syncthreads();

  if (tid == 0) {  // reference-order serial epilogue (absmax 0 x3)
    const float M = MS[0], S = MS[1];
    const float tp = top_ps[row];
    const int kk = top_ks[row];
    const float uu = uin[row];
    float cum = 0.f;
    float qa[kTop];
#pragma unroll
    for (int r = 0; r < kTop; ++r) {
      float pr = expf(tv[r] - M) / S;          // prob of rank r
      cum += pr;
      float cb = cum - pr;                     // cumulative BEFORE this token
      qa[r] = ((cb > tp) || (r >= kk)) ? 0.f : pr;
    }
    const float q0 = qa[0];                    // rank 0 never masked
    float tot = 0.f;
    float cdfa[kTop];
#pragma unroll
    for (int r = 0; r < kTop; ++r) {
      float sr = qa[r] / q0;
      sv[r] = sr;
      tot += sr;
      cdfa[r] = tot;
    }
    const float rth = uu * tot;
    int cnt = 0;
#pragma unroll
    for (int r = 0; r < kTop; ++r) cnt += (cdfa[r] < rth) ? 1 : 0;
    if (cnt > kTop - 1) cnt = kTop - 1;
    out[row] = (float)ti[cnt];                 // sampled token id
    out[kB + row] = 1.0f;                      // success
  }
  __syncthreads();
  if (tid < kTop) out[2 * kB + (size_t)row * kV + tid] = sv[tid];

  // Tail zero-fill: float4 indices 16..2003 (cols 64..8015 of split 0).
  for (int f = 16 + tid; f < kSplit4; f += kT1) out4[f] = z4;
}
}  // namespace

extern "C" void kernel_launch(void* const* d_in, const int* in_sizes, int n_in,
                              void* d_out, int out_size, void* d_ws, size_t ws_size,
                              hipStream_t stream) {
  const float* logits = (const float*)d_in[0];
  const float* temps  = (const float*)d_in[1];
  const int*   top_ks = (const int*)d_in[2];
  const float* top_ps = (const float*)d_in[3];
  const float* uin    = (const float*)d_in[4];
  float* out = (float*)d_out;

  // workspace layout (~1.1 MB)
  float* wm = (float*)d_ws;                          // [B*Splits] split max (y-space)
  float* wS = wm + kB * kSplits;                     // [B*Splits] split sumexp
  unsigned long long* wpk =                          // [B*Splits*Top] sorted top-64
      (unsigned long long*)(wS + kB * kSplits + kB * kSplits);

  k_select<<<dim3(kSplits, kB), kT1, 0, stream>>>(logits, temps, wm, wS, wpk);
  k_sample<<<dim3(kSplits, kB), kT1, 0, stream>>>(temps, top_ks, top_ps, uin,
                                                  wm, wS, wpk, out);
}

// Round 10
// 50.999 us; speedup vs baseline: 1.3392x; 1.3392x over previous
//
#include <hip/hip_runtime.h>
#include <math.h>

namespace {
constexpr int kB = 128;
constexpr int kV = 128256;
constexpr int kSplits = 16;
constexpr int kSplit = kV / kSplits;   // 8016
constexpr int kSplit4 = kSplit / 4;    // 2004 float4
constexpr int kT1 = 256;
constexpr int kE = 8;                  // float4 regs/thread: 8*256=2048 >= 2004
constexpr int kCap = 256;              // candidate cap (== kT1, 1 per thread)
constexpr int kTop = 64;               // max top_k

using f4v = __attribute__((ext_vector_type(4))) float;

// monotonic uint key: ascending key <=> ascending float (finite, non-NaN)
__device__ __forceinline__ unsigned fkey(float y) {
  unsigned u = __float_as_uint(y);
  return ((int)u < 0) ? ~u : (u | 0x80000000u);
}
__device__ __forceinline__ float keyinv(unsigned k) {
  unsigned u = (k & 0x80000000u) ? (k & 0x7fffffffu) : ~k;
  return __uint_as_float(u);
}

__global__ __launch_bounds__(kT1) void k_select(
    const float* __restrict__ logits, const float* __restrict__ temps,
    float* __restrict__ out,
    float* __restrict__ wm, float* __restrict__ wS,
    unsigned long long* __restrict__ wpk) {
  const int sp = blockIdx.x, row = blockIdx.y, tid = threadIdx.x;
  const int lane = tid & 63, wid = tid >> 6;
  __shared__ float wred[4];
  __shared__ float ssum[4];
  __shared__ int cnt2[2][4];
  __shared__ unsigned long long cand[kCap];
  __shared__ int scnt;

  if (tid == 0) scnt = 0;
  const float t = temps[row];
  const float invt = 1.0f / t;
  const size_t rowbase = (size_t)row * kV + (size_t)sp * kSplit;
  const float4* in4 = (const float4*)(logits + rowbase);
  f4v* out4 = (f4v*)(out + 2 * kB + rowbase);
  const float nI = -INFINITY;

  // Load RAW logits into registers (selection order is temperature-
  // invariant: l -> l/t strictly monotone). Loads only before B1.
  float4 r[kE];
  float m = nI;
#pragma unroll
  for (int e = 0; e < kE; ++e) {
    int f = tid + e * kT1;
    float4 l;
    if (f < kSplit4) l = in4[f];
    else l = make_float4(nI, nI, nI, nI);
    r[e] = l;
    m = fmaxf(m, fmaxf(fmaxf(l.x, l.y), fmaxf(l.z, l.w)));
  }
  // Wave shfl max (order-exact) + 4-slot combine: 1 barrier.
  for (int o = 32; o; o >>= 1) m = fmaxf(m, __shfl_xor(m, o));
  if (lane == 0) wred[wid] = m;
  __syncthreads();                                   // B1 (waits loads only)
  const float M = fmaxf(fmaxf(wred[0], wred[1]), fmaxf(wred[2], wred[3]));
  const float My = M / t;     // == max(l/t) bitwise (monotone IEEE div)
  const float negMy = -My;

  // Zero-fill this split's output region with NONTEMPORAL stores: zeros
  // are never read this call, so bypass L2 (no write-allocate thrash of
  // the logit working set). Issued after B1 so no barrier waits on loads
  // + stores together; acks drain under the ~20us of compute below.
  {
    const f4v z4 = {0.f, 0.f, 0.f, 0.f};
#pragma unroll
    for (int e = 0; e < kE; ++e) {
      int f = tid + e * kT1;
      if (f < kSplit4) __builtin_nontemporal_store(z4, out4 + f);
    }
  }

  // Fast softmax partial sum: exp((l - M)/t) via fma + __expf (v_exp);
  // wave shfl-add butterfly + fixed 4-slot combine (validated absmax 0).
  float s = 0.f;
#pragma unroll
  for (int e = 0; e < kE; ++e) {
    s += __expf(fmaf(r[e].x, invt, negMy));
    s += __expf(fmaf(r[e].y, invt, negMy));
    s += __expf(fmaf(r[e].z, invt, negMy));
    s += __expf(fmaf(r[e].w, invt, negMy));
  }
  for (int o = 32; o; o >>= 1) s += __shfl_xor(s, o);
  if (lane == 0) ssum[wid] = s;
  __syncthreads();                                   // B2
  const float Ssp = ssum[0] + ssum[1] + ssum[2] + ssum[3];

  // Binary-search threshold T (key space), count(l >= T) in [64,256].
  // Ballot+popcount counting; double-buffered slots -> 1 barrier/iter.
  // Warm probes M-3, M-4.5 are bracket hints only; bisection stays exact.
  unsigned lo = 0x00800000u;          // below all finite values
  unsigned hi = fkey(M) + 1;          // count 0
  for (int it = 0; it < 32 && hi - lo > 1; ++it) {
    unsigned mid = lo + ((hi - lo) >> 1);
    if (it == 0) {
      unsigned p0 = fkey(M - 3.0f);
      if (p0 > lo && p0 < hi) mid = p0;
    } else if (it == 1) {
      unsigned p1 = fkey(M - 4.5f);
      if (p1 > lo && p1 < hi) mid = p1;
    }
    const float mf = keyinv(mid);
    int cw = 0;
#pragma unroll
    for (int e = 0; e < kE; ++e) {
      cw += (int)__popcll(__ballot(r[e].x >= mf));
      cw += (int)__popcll(__ballot(r[e].y >= mf));
      cw += (int)__popcll(__ballot(r[e].z >= mf));
      cw += (int)__popcll(__ballot(r[e].w >= mf));
    }
    if (lane == 0) cnt2[it & 1][wid] = cw;
    __syncthreads();                                 // B3..~B5
    const int c = cnt2[it & 1][0] + cnt2[it & 1][1] +
                  cnt2[it & 1][2] + cnt2[it & 1][3];
    if (c >= kTop) { lo = mid; if (c <= kCap) break; }
    else hi = mid;
  }
  const float Tf = keyinv(lo);

  // Collect candidates (raw-float compare; fkey only for survivors).
  // Pack (fkey(l), ~idx): u64 desc == value desc, index asc.
#pragma unroll
  for (int e = 0; e < kE; ++e) {
    int f = tid + e * kT1;
    const float vals[4] = {r[e].x, r[e].y, r[e].z, r[e].w};
#pragma unroll
    for (int j = 0; j < 4; ++j) {
      const float lv = vals[j];
      if (lv >= Tf) {
        int pos = atomicAdd(&scnt, 1);
        if (pos < kCap)
          cand[pos] = ((unsigned long long)fkey(lv) << 32) |
                      (unsigned)~(unsigned)(sp * kSplit + f * 4 + j);
      }
    }
  }
  __syncthreads();                                   // B6
  const int nc = scnt < kCap ? scnt : kCap;
  unsigned long long v = (tid < nc) ? cand[tid] : 0ULL;

  // Bitonic sort 256 desc, one element/thread. Stages with j<64 exchange
  // in-wave via shfl_xor (no barrier); only j in {64,128} use LDS.
  for (int k2 = 2; k2 <= kCap; k2 <<= 1) {
    for (int j = k2 >> 1; j; j >>= 1) {
      unsigned long long o;
      if (j < 64) {
        o = __shfl_xor(v, j);
      } else {
        __syncthreads();         // all prior reads of cand done
        cand[tid] = v;
        __syncthreads();
        o = cand[tid ^ j];
      }
      const bool keep_max = (((tid & k2) == 0) == ((tid & j) == 0));
      v = keep_max ? (o > v ? o : v) : (o < v ? o : v);
    }
  }

  if (tid < kTop)
    wpk[((size_t)row * kSplits + sp) * kTop + tid] = v;
  if (tid == 0) {
    wm[row * kSplits + sp] = My;
    wS[row * kSplits + sp] = Ssp;
  }
}

__global__ __launch_bounds__(kT1) void k_sample(
    const float* __restrict__ temps,
    const int* __restrict__ top_ks, const float* __restrict__ top_ps,
    const float* __restrict__ uin,
    const float* __restrict__ wm, const float* __restrict__ wS,
    const unsigned long long* __restrict__ wpk, float* __restrict__ out) {
  const int row = blockIdx.x, tid = threadIdx.x;
  constexpr int kN = kSplits * kTop;   // 1024
  __shared__ unsigned long long pk[kN];
  __shared__ float mArr[kSplits], sArr[kSplits];
  __shared__ float tv[kTop];
  __shared__ int ti[kTop];
  __shared__ float sv[kTop];
  __shared__ float MS[2];

  if (tid < kSplits) {
    mArr[tid] = wm[row * kSplits + tid];
    sArr[tid] = wS[row * kSplits + tid];
  }
  for (int i = tid; i < kN; i += kT1)
    pk[i] = wpk[(size_t)row * kN + i];
  __syncthreads();
  if (tid == 0) {  // fixed-order merge of split (m, S) partials
    float M = -INFINITY;
    for (int s2 = 0; s2 < kSplits; ++s2) M = fmaxf(M, mArr[s2]);
    float S = 0.f;
    for (int s2 = 0; s2 < kSplits; ++s2) S += expf(mArr[s2] - M) * sArr[s2];
    MS[0] = M; MS[1] = S;
  }

  // Bitonic top-64 merge: 4 rounds of (cross-compare + 6 cleanup stages).
  for (int r = 0; r < 4; ++r) {
    const int pairs = 8 >> r;
    __syncthreads();
    for (int w = tid; w < pairs * 64; w += kT1) {
      int q = w >> 6, i = w & 63;
      int a = q * (128 << r), b = a + (64 << r);
      unsigned long long x = pk[a + i], y = pk[b + 63 - i];
      pk[a + i] = x > y ? x : y;      // top-64 multiset, bitonic order
    }
    for (int j = 32; j; j >>= 1) {    // desc bitonic merge of each kept run
      __syncthreads();
      for (int w = tid; w < pairs * 32; w += kT1) {
        int q = w >> 5, z = w & 31;
        int a = q * (128 << r);
        int i = ((z & ~(j - 1)) << 1) | (z & (j - 1));
        unsigned long long x = pk[a + i], y = pk[a + i + j];
        if (x < y) { pk[a + i] = y; pk[a + i + j] = x; }
      }
    }
  }
  __syncthreads();

  if (tid < kTop) {
    unsigned long long p2 = pk[tid];
    // keys are fkey(raw logit); exact IEEE l/t gives the reference's tv.
    tv[tid] = keyinv((unsigned)(p2 >> 32)) / temps[row];
    ti[tid] = (int)(~(unsigned)(p2 & 0xffffffffu));
  }
  __syncthreads();

  if (tid == 0) {  // reference-order serial epilogue (absmax 0 across rounds)
    const float M = MS[0], S = MS[1];
    const float tp = top_ps[row];
    const int kk = top_ks[row];
    const float uu = uin[row];
    float cum = 0.f;
    float qa[kTop];
#pragma unroll
    for (int r = 0; r < kTop; ++r) {
      float pr = expf(tv[r] - M) / S;          // prob of rank r
      cum += pr;
      float cb = cum - pr;                     // cumulative BEFORE this token
      qa[r] = ((cb > tp) || (r >= kk)) ? 0.f : pr;
    }
    const float q0 = qa[0];                    // rank 0 never masked
    float tot = 0.f;
    float cdfa[kTop];
#pragma unroll
    for (int r = 0; r < kTop; ++r) {
      float sr = qa[r] / q0;
      sv[r] = sr;
      tot += sr;
      cdfa[r] = tot;
    }
    const float rth = uu * tot;
    int cnt = 0;
#pragma unroll
    for (int r = 0; r < kTop; ++r) cnt += (cdfa[r] < rth) ? 1 : 0;
    if (cnt > kTop - 1) cnt = kTop - 1;
    out[row] = (float)ti[cnt];                 // sampled token id
    out[kB + row] = 1.0f;                      // success
  }
  __syncthreads();
  if (tid < kTop) out[2 * kB + (size_t)row * kV + tid] = sv[tid];
}
}  // namespace

extern "C" void kernel_launch(void* const* d_in, const int* in_sizes, int n_in,
                              void* d_out, int out_size, void* d_ws, size_t ws_size,
                              hipStream_t stream) {
  const float* logits = (const float*)d_in[0];
  const float* temps  = (const float*)d_in[1];
  const int*   top_ks = (const int*)d_in[2];
  const float* top_ps = (const float*)d_in[3];
  const float* uin    = (const float*)d_in[4];
  float* out = (float*)d_out;

  // workspace layout (~1.1 MB)
  float* wm = (float*)d_ws;                          // [B*Splits] split max (y-space)
  float* wS = wm + kB * kSplits;                     // [B*Splits] split sumexp
  unsigned long long* wpk =                          // [B*Splits*Top] sorted top-64
      (unsigned long long*)(wS + kB * kSplits + kB * kSplits);

  k_select<<<dim3(kSplits, kB), kT1, 0, stream>>>(logits, temps, out, wm, wS, wpk);
  k_sample<<<kB, kT1, 0, stream>>>(temps, top_ks, top_ps, uin, wm, wS, wpk, out);
}